// Round 11
// baseline (1970.615 us; speedup 1.0000x reference)
//
#include <hip/hip_runtime.h>
#include <math.h>

#define B 256
#define C 1024
#define D 512
#define M 4096
#define KS_SC 4    // K-split for score GEMM (K=1024 -> 256 per slice)
#define KS_MR 8    // K-split for mr GEMM    (K=4096 -> 512 per slice)
#define CHUNK 64   // b-chunk: 128 MB feature slice stays L3-resident for k_fg
#define CPB 32     // c-rows per colmean block
#define NCP (C / CPB)  // 32 c-partials per b
static constexpr float EPS = 1e-12f;

typedef float fx4 __attribute__((ext_vector_type(4)));   // nontemporal-OK
typedef short bf16x8 __attribute__((ext_vector_type(8))); // 8 bf16 = 4 VGPR
typedef float f32x4 __attribute__((ext_vector_type(4)));  // MFMA accumulator

static __device__ __forceinline__ unsigned short f2bf(float x) {
    unsigned u = __builtin_bit_cast(unsigned, x);
    return (unsigned short)((u + 0x7fffu + ((u >> 16) & 1u)) >> 16);  // RNE
}

// ---------------- K0: memory f32 -> memB bf16 [M][C] + memBT bf16 [C][M] ---
// also zeroes the ticket counters each launch (graph-replay safe)
__global__ __launch_bounds__(256) void k_convmem(const float* __restrict__ mem,
                                                 unsigned short* __restrict__ memB,
                                                 unsigned short* __restrict__ memBT,
                                                 int* __restrict__ cntA,
                                                 int* __restrict__ cntM) {
    __shared__ unsigned short lds[64][65];
    int t = threadIdx.x;
    if (blockIdx.x == 0 && blockIdx.y == 0) {
        cntA[t] = 0;                 // B == 256 counters
        if (t < 64) cntM[t] = 0;     // 64 mr-tile counters
    }
    int tm = blockIdx.x * 64;   // M-tile
    int tc = blockIdx.y * 64;   // C-tile
    int rr = t >> 4, c4 = t & 15;
#pragma unroll
    for (int i = 0; i < 4; ++i) {
        int row = rr + 16 * i;
        float4 v = *reinterpret_cast<const float4*>(mem + (size_t)(tm + row) * C + tc + c4 * 4);
        unsigned short b0 = f2bf(v.x), b1 = f2bf(v.y), b2 = f2bf(v.z), b3 = f2bf(v.w);
        ushort4 w = make_ushort4(b0, b1, b2, b3);
        *reinterpret_cast<ushort4*>(memB + (size_t)(tm + row) * C + tc + c4 * 4) = w;
        lds[row][c4 * 4 + 0] = b0; lds[row][c4 * 4 + 1] = b1;
        lds[row][c4 * 4 + 2] = b2; lds[row][c4 * 4 + 3] = b3;
    }
    __syncthreads();
#pragma unroll
    for (int i = 0; i < 4; ++i) {
        int colC = rr + 16 * i;
        ushort4 w = make_ushort4(lds[c4 * 4 + 0][colC], lds[c4 * 4 + 1][colC],
                                 lds[c4 * 4 + 2][colC], lds[c4 * 4 + 3][colC]);
        *reinterpret_cast<ushort4*>(memBT + (size_t)(tc + colC) * M + tm + c4 * 4) = w;
    }
}

// ---------------- K1 (fused colmean+attn): partial col-sums; the last block
// per row b (device-scope ticket) computes softmax(colsum/C)/D -> attnD -----
__global__ __launch_bounds__(256) void k_colmean(const float* __restrict__ f,
                                                 float* __restrict__ colpart,
                                                 float* __restrict__ attnD,
                                                 int* __restrict__ cntA, int b0) {
    __shared__ fx4 buf[128];
    __shared__ float red[256];
    __shared__ int sflag;
    int bx = blockIdx.x, cc = blockIdx.y;
    int b = b0 + bx;
    int t = threadIdx.x;
    int r = t >> 7, lane = t & 127;
    const fx4* f4 = reinterpret_cast<const fx4*>(f)
                  + ((size_t)b * C + cc * CPB + r * 16) * (D / 4) + lane;
    fx4 acc = (fx4)(0.f);
#pragma unroll
    for (int k = 0; k < 16; ++k) acc += f4[(size_t)k * (D / 4)];
    if (r) buf[lane] = acc;
    __syncthreads();
    if (!r) {
        acc += buf[lane];
        reinterpret_cast<fx4*>(colpart)[((size_t)cc * B + b) * (D / 4) + lane] = acc;
    }
    // ---- ticket: last block for this b does the attn reduction ----
    __threadfence();
    __syncthreads();
    if (t == 0) sflag = (atomicAdd(&cntA[b], 1) == NCP - 1);
    __syncthreads();
    if (sflag) {
        __threadfence();
        float s0 = 0.f, s1 = 0.f;
#pragma unroll
        for (int p = 0; p < NCP; ++p) {
            s0 += colpart[((size_t)p * B + b) * D + t];
            s1 += colpart[((size_t)p * B + b) * D + t + 256];
        }
        float x0 = s0 * (1.0f / C), x1 = s1 * (1.0f / C);
        red[t] = fmaxf(x0, x1); __syncthreads();
        for (int s = 128; s > 0; s >>= 1) {
            if (t < s) red[t] = fmaxf(red[t], red[t + s]);
            __syncthreads();
        }
        float mx = red[0]; __syncthreads();
        float e0 = expf(x0 - mx), e1 = expf(x1 - mx);
        red[t] = e0 + e1; __syncthreads();
        for (int s = 128; s > 0; s >>= 1) {
            if (t < s) red[t] += red[t + s];
            __syncthreads();
        }
        float inv = 1.0f / (red[0] * (float)D);
        attnD[(size_t)b * D + t] = e0 * inv;
        attnD[(size_t)b * D + t + 256] = e1 * inv;
    }
}

// ---------------- K3: fG[b][c] (+ bf16 copy) = sum_d f*attn ----------------
__global__ __launch_bounds__(256) void k_fg(const float* __restrict__ f,
                                            const float* __restrict__ attnD,
                                            float* __restrict__ fG,
                                            unsigned short* __restrict__ fGB, int b0) {
    int w = blockIdx.x * 4 + (threadIdx.x >> 6);
    int lane = threadIdx.x & 63;
    int b = b0 + (w >> 10);
    int c = w & 1023;
    const float4* f4 = reinterpret_cast<const float4*>(f) + ((size_t)b * C + c) * (D / 4);
    const float4* a4 = reinterpret_cast<const float4*>(attnD) + (size_t)b * (D / 4);
    float4 v0 = f4[lane], v1 = f4[lane + 64];
    float4 a0 = a4[lane], a1 = a4[lane + 64];
    float acc = v0.x * a0.x + v0.y * a0.y + v0.z * a0.z + v0.w * a0.w
              + v1.x * a1.x + v1.y * a1.y + v1.z * a1.z + v1.w * a1.w;
    for (int s = 32; s > 0; s >>= 1) acc += __shfl_xor(acc, s, 64);
    if (lane == 0) {
        fG[(size_t)b * C + c] = acc;
        fGB[(size_t)b * C + c] = f2bf(acc);
    }
}

// ---------------- K4: score_p[z][b][m] MFMA bf16 (64x64 tile, no LDS) ------
__global__ __launch_bounds__(256) void k_score(const unsigned short* __restrict__ fGB,
                                               const unsigned short* __restrict__ memB,
                                               float* __restrict__ score_p) {
    int t = threadIdx.x;
    int lane = t & 63, wid = t >> 6;
    int wm = wid >> 1, wn = wid & 1;
    int brow = blockIdx.y * 64 + wm * 32;
    int mcol = blockIdx.x * 64 + wn * 32;
    int kc0 = blockIdx.z * (C / KS_SC);
    int l16 = lane & 15, kg = lane >> 4;
    f32x4 acc00 = {}, acc01 = {}, acc10 = {}, acc11 = {};
#pragma unroll
    for (int ks = 0; ks < C / KS_SC / 32; ++ks) {
        int kb = kc0 + ks * 32 + kg * 8;
        bf16x8 a0 = *reinterpret_cast<const bf16x8*>(fGB + (size_t)(brow + l16) * C + kb);
        bf16x8 a1 = *reinterpret_cast<const bf16x8*>(fGB + (size_t)(brow + 16 + l16) * C + kb);
        bf16x8 b0 = *reinterpret_cast<const bf16x8*>(memB + (size_t)(mcol + l16) * C + kb);
        bf16x8 b1 = *reinterpret_cast<const bf16x8*>(memB + (size_t)(mcol + 16 + l16) * C + kb);
        acc00 = __builtin_amdgcn_mfma_f32_16x16x32_bf16(a0, b0, acc00, 0, 0, 0);
        acc01 = __builtin_amdgcn_mfma_f32_16x16x32_bf16(a0, b1, acc01, 0, 0, 0);
        acc10 = __builtin_amdgcn_mfma_f32_16x16x32_bf16(a1, b0, acc10, 0, 0, 0);
        acc11 = __builtin_amdgcn_mfma_f32_16x16x32_bf16(a1, b1, acc11, 0, 0, 0);
    }
    float* o = score_p + (size_t)blockIdx.z * B * M;
#pragma unroll
    for (int r = 0; r < 4; ++r) {
        int row0 = brow + kg * 4 + r, row1 = row0 + 16;
        o[(size_t)row0 * M + mcol + l16]      = acc00[r];
        o[(size_t)row0 * M + mcol + 16 + l16] = acc01[r];
        o[(size_t)row1 * M + mcol + l16]      = acc10[r];
        o[(size_t)row1 * M + mcol + 16 + l16] = acc11[r];
    }
}

// ---------------- K5: combine partials -> scoreF; row softmax; argmax ------
__global__ __launch_bounds__(1024) void k_rowsoftmax(const float* __restrict__ score_p,
                                                     float* __restrict__ scoreF,
                                                     unsigned short* __restrict__ simgB,
                                                     int* __restrict__ idxout,
                                                     float* __restrict__ rowinv) {
    __shared__ float srow[M];
    __shared__ float rv[1024];
    __shared__ int ri[1024];
    int b = blockIdx.x, t = threadIdx.x;
    const float* p = score_p + (size_t)b * M;
    float mx = -INFINITY; int mi = 0;
    for (int j = t; j < M; j += 1024) {
        float s = p[j] + p[j + (size_t)B * M] + p[j + 2 * (size_t)B * M]
                + p[j + 3 * (size_t)B * M];
        srow[j] = s;
        scoreF[(size_t)b * M + j] = s;
        if (s > mx) { mx = s; mi = j; }
    }
    rv[t] = mx; ri[t] = mi; __syncthreads();
    for (int s = 512; s > 0; s >>= 1) {
        if (t < s) {
            if (rv[t + s] > rv[t] || (rv[t + s] == rv[t] && ri[t + s] < ri[t])) {
                rv[t] = rv[t + s]; ri[t] = ri[t + s];
            }
        }
        __syncthreads();
    }
    float rmax = rv[0]; int rid = ri[0];
    __syncthreads();
    float s = 0.f;
    for (int j = t; j < M; j += 1024) {
        float e = expf(srow[j] - rmax);
        simgB[(size_t)b * M + j] = f2bf(e);  // unnormalized; 1/rowsum in mr-reduce
        s += e;
    }
    rv[t] = s; __syncthreads();
    for (int ss = 512; ss > 0; ss >>= 1) {
        if (t < ss) rv[t] += rv[t + ss];
        __syncthreads();
    }
    if (t == 0) { idxout[b] = rid; rowinv[b] = 1.0f / rv[0]; }
}

// ---------------- K6 (fused mr+mrred): MFMA partials; last K-split block per
// 64x64 tile (device ticket) sums partials + fG + rowinv -> mrf -------------
__global__ __launch_bounds__(256) void k_mr(const unsigned short* __restrict__ simgB,
                                            const unsigned short* __restrict__ memBT,
                                            const float* __restrict__ fG,
                                            const float* __restrict__ rowinv,
                                            float* __restrict__ mr_p,
                                            float* __restrict__ mrf,
                                            int* __restrict__ cntM) {
    __shared__ int sflag;
    int t = threadIdx.x;
    int lane = t & 63, wid = t >> 6;
    int wm = wid >> 1, wn = wid & 1;
    int br0 = blockIdx.y * 64, cc0 = blockIdx.x * 64;
    int brow = br0 + wm * 32;
    int ccol = cc0 + wn * 32;
    int kc0 = blockIdx.z * (M / KS_MR);
    int l16 = lane & 15, kg = lane >> 4;
    f32x4 acc00 = {}, acc01 = {}, acc10 = {}, acc11 = {};
#pragma unroll 4
    for (int ks = 0; ks < M / KS_MR / 32; ++ks) {
        int kb = kc0 + ks * 32 + kg * 8;
        bf16x8 a0 = *reinterpret_cast<const bf16x8*>(simgB + (size_t)(brow + l16) * M + kb);
        bf16x8 a1 = *reinterpret_cast<const bf16x8*>(simgB + (size_t)(brow + 16 + l16) * M + kb);
        bf16x8 b0 = *reinterpret_cast<const bf16x8*>(memBT + (size_t)(ccol + l16) * M + kb);
        bf16x8 b1 = *reinterpret_cast<const bf16x8*>(memBT + (size_t)(ccol + 16 + l16) * M + kb);
        acc00 = __builtin_amdgcn_mfma_f32_16x16x32_bf16(a0, b0, acc00, 0, 0, 0);
        acc01 = __builtin_amdgcn_mfma_f32_16x16x32_bf16(a0, b1, acc01, 0, 0, 0);
        acc10 = __builtin_amdgcn_mfma_f32_16x16x32_bf16(a1, b0, acc10, 0, 0, 0);
        acc11 = __builtin_amdgcn_mfma_f32_16x16x32_bf16(a1, b1, acc11, 0, 0, 0);
    }
    float* o = mr_p + (size_t)blockIdx.z * B * C;
#pragma unroll
    for (int r = 0; r < 4; ++r) {
        int row0 = brow + kg * 4 + r, row1 = row0 + 16;
        o[(size_t)row0 * C + ccol + l16]      = acc00[r];
        o[(size_t)row0 * C + ccol + 16 + l16] = acc01[r];
        o[(size_t)row1 * C + ccol + l16]      = acc10[r];
        o[(size_t)row1 * C + ccol + 16 + l16] = acc11[r];
    }
    // ---- ticket: last z-block for this tile reduces partials -> mrf ----
    int tile = blockIdx.y * gridDim.x + blockIdx.x;   // 4*16 = 64 tiles
    __threadfence();
    __syncthreads();
    if (t == 0) sflag = (atomicAdd(&cntM[tile], 1) == KS_MR - 1);
    __syncthreads();
    if (sflag) {
        __threadfence();
        int row = t >> 2;               // 0..63 within tile
        int gr = br0 + row;
        float rinv = rowinv[gr];
#pragma unroll
        for (int q = 0; q < 4; ++q) {
            int gc = cc0 + (t & 3) * 16 + q * 4;
            float4 a = *reinterpret_cast<const float4*>(fG + (size_t)gr * C + gc);
#pragma unroll
            for (int z = 0; z < KS_MR; ++z) {
                float4 v = *reinterpret_cast<const float4*>(
                    mr_p + (size_t)z * B * C + (size_t)gr * C + gc);
                a.x += rinv * v.x; a.y += rinv * v.y;
                a.z += rinv * v.z; a.w += rinv * v.w;
            }
            *reinterpret_cast<float4*>(mrf + (size_t)gr * C + gc) = a;
        }
    }
}

// ---------------- K7: out = feature + mrf, rows DESCENDING -----------------
__global__ __launch_bounds__(256) void k_out(const float* __restrict__ f,
                                             const float* __restrict__ mrf,
                                             float* __restrict__ out) {
    size_t n4 = (size_t)B * C * D / 4;
    const fx4* f4 = reinterpret_cast<const fx4*>(f);
    fx4* o4 = reinterpret_cast<fx4*>(out);
    for (size_t i = (size_t)blockIdx.x * blockDim.x + threadIdx.x; i < n4;
         i += (size_t)gridDim.x * blockDim.x) {
        size_t row = (size_t)B * C - 1 - (i >> 7);
        size_t j = i & 127;
        size_t o = row * 128 + j;
        fx4 v = f4[o];
        v += mrf[row];
        __builtin_nontemporal_store(v, o4 + o);
    }
}

// ---------------- K8: updated_memory row m (wts inline + L2-normalize) -----
__global__ __launch_bounds__(256) void k_memupd(const float* __restrict__ mem,
                                                const float* __restrict__ fG,
                                                const int* __restrict__ idx,
                                                const float* __restrict__ scoreF,
                                                float* __restrict__ out2) {
    int m = blockIdx.x, t = threadIdx.x;
    __shared__ int sIdx[B];
    __shared__ float se[B];
    __shared__ float red[256];
    __shared__ int sAny;
    if (t == 0) sAny = 0;
    __syncthreads();
    sIdx[t] = idx[t];
    __syncthreads();
    if (sIdx[t] == m) sAny = 1;   // benign same-value race
    __syncthreads();

    const fx4* m4 = reinterpret_cast<const fx4*>(mem) + (size_t)m * (C / 4);
    fx4 u = m4[t];
    if (sAny) {
        float x = scoreF[(size_t)t * M + m];
        red[t] = x; __syncthreads();
        for (int s = 128; s > 0; s >>= 1) {
            if (t < s) red[t] = fmaxf(red[t], red[t + s]);
            __syncthreads();
        }
        float mx = red[0]; __syncthreads();
        float e = expf(x - mx);
        se[t] = e;
        red[t] = e; __syncthreads();
        for (int s = 128; s > 0; s >>= 1) {
            if (t < s) red[t] += red[t + s];
            __syncthreads();
        }
        float Sinv = 1.0f / red[0];
        __syncthreads();
        for (int b2 = 0; b2 < B; ++b2) {
            if (sIdx[b2] == m) {
                float w = se[b2] * Sinv;
                fx4 g = reinterpret_cast<const fx4*>(fG)[(size_t)b2 * (C / 4) + t];
                u += g * w;
            }
        }
    }
    red[t] = u.x * u.x + u.y * u.y + u.z * u.z + u.w * u.w;
    __syncthreads();
    for (int s = 128; s > 0; s >>= 1) {
        if (t < s) red[t] += red[t + s];
        __syncthreads();
    }
    float invn = 1.0f / fmaxf(sqrtf(red[0]), EPS);
    reinterpret_cast<fx4*>(out2)[(size_t)m * (C / 4) + t] = u * invn;
}

extern "C" void kernel_launch(void* const* d_in, const int* in_sizes, int n_in,
                              void* d_out, int out_size, void* d_ws, size_t ws_size,
                              hipStream_t stream) {
    const float* feature = (const float*)d_in[0];  // [B,C,D]
    const float* memory  = (const float*)d_in[1];  // [M,C]
    float* out = (float*)d_out;

    // workspace layout: f32 buffers, counters, then u16 buffers
    float* ws = (float*)d_ws;
    float* colpart = ws;                                  // NCP*B*D = 16 MB
    float* attnD   = colpart + (size_t)NCP * B * D;       // B*D
    float* fG      = attnD + (size_t)B * D;               // B*C
    float* scoreF  = fG + (size_t)B * C;                  // B*M
    float* score_p = scoreF + (size_t)B * M;              // KS_SC*B*M = 16 MB
    float* mr_p    = score_p + (size_t)KS_SC * B * M;     // KS_MR*B*C = 8 MB
    float* mrf     = mr_p + (size_t)KS_MR * B * C;        // B*C
    float* rowinv  = mrf + (size_t)B * C;                 // B
    int*   idx     = (int*)(rowinv + B);                  // B
    int*   cntA    = idx + B;                             // B tickets (attn)
    int*   cntM    = cntA + B;                            // 64 tickets (mr tiles)
    unsigned short* fGB   = (unsigned short*)(cntM + 64); // B*C u16
    unsigned short* memB  = fGB + (size_t)B * C;          // M*C u16 = 8 MB
    unsigned short* memBT = memB + (size_t)M * C;         // C*M u16 = 8 MB
    unsigned short* simgB = memBT + (size_t)C * M;        // B*M u16 = 2 MB

    k_convmem<<<dim3(M / 64, C / 64), 256, 0, stream>>>(memory, memB, memBT, cntA, cntM);
    for (int b0 = 0; b0 < B; b0 += CHUNK) {
        k_colmean<<<dim3(CHUNK, NCP), 256, 0, stream>>>(feature, colpart, attnD, cntA, b0);
        k_fg<<<CHUNK * C / 4, 256, 0, stream>>>(feature, attnD, fG, fGB, b0);
    }
    k_score<<<dim3(M / 64, B / 64, KS_SC), 256, 0, stream>>>(fGB, memB, score_p);
    k_rowsoftmax<<<B, 1024, 0, stream>>>(score_p, scoreF, simgB, idx, rowinv);
    k_mr<<<dim3(C / 64, B / 64, KS_MR), 256, 0, stream>>>(simgB, memBT, fG, rowinv,
                                                          mr_p, mrf, cntM);
    k_out<<<4096, 256, 0, stream>>>(feature, mrf, out);
    k_memupd<<<M, 256, 0, stream>>>(memory, fG, idx, scoreF, out + (size_t)B * C * D);
}

// Round 12
// 458.576 us; speedup vs baseline: 4.2972x; 4.2972x over previous
//
#include <hip/hip_runtime.h>
#include <math.h>

#define B 256
#define C 1024
#define D 512
#define M 4096
#define KS_SC 4    // K-split for score GEMM (K=1024 -> 256 per slice)
#define KS_MR 8    // K-split for mr GEMM    (K=4096 -> 512 per slice)
#define CHUNK 64   // b-chunk: 128 MB feature slice stays L3-resident for k_fg
#define CPB 32     // c-rows per colmean block
#define NCP (C / CPB)  // 32 c-partials per b
static constexpr float EPS = 1e-12f;

typedef float fx4 __attribute__((ext_vector_type(4)));   // nontemporal-OK
typedef short bf16x8 __attribute__((ext_vector_type(8))); // 8 bf16 = 4 VGPR
typedef float f32x4 __attribute__((ext_vector_type(4)));  // MFMA accumulator

static __device__ __forceinline__ unsigned short f2bf(float x) {
    unsigned u = __builtin_bit_cast(unsigned, x);
    return (unsigned short)((u + 0x7fffu + ((u >> 16) & 1u)) >> 16);  // RNE
}

// ---------------- K0: memory f32 -> memB bf16 [M][C] + memBT bf16 [C][M] ---
__global__ __launch_bounds__(256) void k_convmem(const float* __restrict__ mem,
                                                 unsigned short* __restrict__ memB,
                                                 unsigned short* __restrict__ memBT) {
    __shared__ unsigned short lds[64][65];
    int tm = blockIdx.x * 64;   // M-tile
    int tc = blockIdx.y * 64;   // C-tile
    int t = threadIdx.x;
    int rr = t >> 4, c4 = t & 15;
#pragma unroll
    for (int i = 0; i < 4; ++i) {
        int row = rr + 16 * i;
        float4 v = *reinterpret_cast<const float4*>(mem + (size_t)(tm + row) * C + tc + c4 * 4);
        unsigned short b0 = f2bf(v.x), b1 = f2bf(v.y), b2 = f2bf(v.z), b3 = f2bf(v.w);
        ushort4 w = make_ushort4(b0, b1, b2, b3);
        *reinterpret_cast<ushort4*>(memB + (size_t)(tm + row) * C + tc + c4 * 4) = w;
        lds[row][c4 * 4 + 0] = b0; lds[row][c4 * 4 + 1] = b1;
        lds[row][c4 * 4 + 2] = b2; lds[row][c4 * 4 + 3] = b3;
    }
    __syncthreads();
#pragma unroll
    for (int i = 0; i < 4; ++i) {
        int colC = rr + 16 * i;
        ushort4 w = make_ushort4(lds[c4 * 4 + 0][colC], lds[c4 * 4 + 1][colC],
                                 lds[c4 * 4 + 2][colC], lds[c4 * 4 + 3][colC]);
        *reinterpret_cast<ushort4*>(memBT + (size_t)(tc + colC) * M + tm + c4 * 4) = w;
    }
}

// ---------------- K1: colpart[cc][bl][d] = sum over 32 c-rows ---------------
__global__ __launch_bounds__(256) void k_colmean(const float* __restrict__ f,
                                                 float* __restrict__ colpart, int b0) {
    __shared__ fx4 buf[128];
    int bx = blockIdx.x, cc = blockIdx.y;
    int b = b0 + bx;
    int t = threadIdx.x;
    int r = t >> 7, lane = t & 127;
    const fx4* f4 = reinterpret_cast<const fx4*>(f)
                  + ((size_t)b * C + cc * CPB + r * 16) * (D / 4) + lane;
    fx4 acc = (fx4)(0.f);
#pragma unroll
    for (int k = 0; k < 16; ++k) acc += f4[(size_t)k * (D / 4)];
    if (r) buf[lane] = acc;
    __syncthreads();
    if (!r) {
        acc += buf[lane];
        reinterpret_cast<fx4*>(colpart)[((size_t)cc * CHUNK + bx) * (D / 4) + lane] = acc;
    }
}

// ---------------- K2: attnD[b][d] = softmax_d(colsum/C)/D ------------------
__global__ __launch_bounds__(256) void k_attn(const float* __restrict__ colpart,
                                              float* __restrict__ attnD, int b0) {
    __shared__ float red[256];
    int bl = blockIdx.x;
    int b = b0 + bl;
    int t = threadIdx.x;
    float s0 = 0.f, s1 = 0.f;
#pragma unroll
    for (int p = 0; p < NCP; ++p) {
        s0 += colpart[((size_t)p * CHUNK + bl) * D + t];
        s1 += colpart[((size_t)p * CHUNK + bl) * D + t + 256];
    }
    float x0 = s0 * (1.0f / C), x1 = s1 * (1.0f / C);
    red[t] = fmaxf(x0, x1); __syncthreads();
    for (int s = 128; s > 0; s >>= 1) {
        if (t < s) red[t] = fmaxf(red[t], red[t + s]);
        __syncthreads();
    }
    float mx = red[0]; __syncthreads();
    float e0 = expf(x0 - mx), e1 = expf(x1 - mx);
    red[t] = e0 + e1; __syncthreads();
    for (int s = 128; s > 0; s >>= 1) {
        if (t < s) red[t] += red[t + s];
        __syncthreads();
    }
    float inv = 1.0f / (red[0] * (float)D);
    attnD[(size_t)b * D + t] = e0 * inv;
    attnD[(size_t)b * D + t + 256] = e1 * inv;
}

// ---------------- K3: fG[b][c] (+ bf16 copy) = sum_d f*attn ----------------
__global__ __launch_bounds__(256) void k_fg(const float* __restrict__ f,
                                            const float* __restrict__ attnD,
                                            float* __restrict__ fG,
                                            unsigned short* __restrict__ fGB, int b0) {
    int w = blockIdx.x * 4 + (threadIdx.x >> 6);
    int lane = threadIdx.x & 63;
    int b = b0 + (w >> 10);
    int c = w & 1023;
    const float4* f4 = reinterpret_cast<const float4*>(f) + ((size_t)b * C + c) * (D / 4);
    const float4* a4 = reinterpret_cast<const float4*>(attnD) + (size_t)b * (D / 4);
    float4 v0 = f4[lane], v1 = f4[lane + 64];
    float4 a0 = a4[lane], a1 = a4[lane + 64];
    float acc = v0.x * a0.x + v0.y * a0.y + v0.z * a0.z + v0.w * a0.w
              + v1.x * a1.x + v1.y * a1.y + v1.z * a1.z + v1.w * a1.w;
    for (int s = 32; s > 0; s >>= 1) acc += __shfl_xor(acc, s, 64);
    if (lane == 0) {
        fG[(size_t)b * C + c] = acc;
        fGB[(size_t)b * C + c] = f2bf(acc);
    }
}

// ---------------- K4: score_p[z][b][m] MFMA bf16 (64x64 tile, no LDS) ------
__global__ __launch_bounds__(256) void k_score(const unsigned short* __restrict__ fGB,
                                               const unsigned short* __restrict__ memB,
                                               float* __restrict__ score_p) {
    int t = threadIdx.x;
    int lane = t & 63, wid = t >> 6;
    int wm = wid >> 1, wn = wid & 1;
    int brow = blockIdx.y * 64 + wm * 32;
    int mcol = blockIdx.x * 64 + wn * 32;
    int kc0 = blockIdx.z * (C / KS_SC);
    int l16 = lane & 15, kg = lane >> 4;
    f32x4 acc00 = {}, acc01 = {}, acc10 = {}, acc11 = {};
#pragma unroll
    for (int ks = 0; ks < C / KS_SC / 32; ++ks) {
        int kb = kc0 + ks * 32 + kg * 8;
        bf16x8 a0 = *reinterpret_cast<const bf16x8*>(fGB + (size_t)(brow + l16) * C + kb);
        bf16x8 a1 = *reinterpret_cast<const bf16x8*>(fGB + (size_t)(brow + 16 + l16) * C + kb);
        bf16x8 b0 = *reinterpret_cast<const bf16x8*>(memB + (size_t)(mcol + l16) * C + kb);
        bf16x8 b1 = *reinterpret_cast<const bf16x8*>(memB + (size_t)(mcol + 16 + l16) * C + kb);
        acc00 = __builtin_amdgcn_mfma_f32_16x16x32_bf16(a0, b0, acc00, 0, 0, 0);
        acc01 = __builtin_amdgcn_mfma_f32_16x16x32_bf16(a0, b1, acc01, 0, 0, 0);
        acc10 = __builtin_amdgcn_mfma_f32_16x16x32_bf16(a1, b0, acc10, 0, 0, 0);
        acc11 = __builtin_amdgcn_mfma_f32_16x16x32_bf16(a1, b1, acc11, 0, 0, 0);
    }
    float* o = score_p + (size_t)blockIdx.z * B * M;
#pragma unroll
    for (int r = 0; r < 4; ++r) {
        int row0 = brow + kg * 4 + r, row1 = row0 + 16;
        o[(size_t)row0 * M + mcol + l16]      = acc00[r];
        o[(size_t)row0 * M + mcol + 16 + l16] = acc01[r];
        o[(size_t)row1 * M + mcol + l16]      = acc10[r];
        o[(size_t)row1 * M + mcol + 16 + l16] = acc11[r];
    }
}

// ---------------- K5: combine partials -> scoreF; row softmax; argmax ------
__global__ __launch_bounds__(1024) void k_rowsoftmax(const float* __restrict__ score_p,
                                                     float* __restrict__ scoreF,
                                                     unsigned short* __restrict__ simgB,
                                                     int* __restrict__ idxout,
                                                     float* __restrict__ rowinv) {
    __shared__ float srow[M];
    __shared__ float rv[1024];
    __shared__ int ri[1024];
    int b = blockIdx.x, t = threadIdx.x;
    const float* p = score_p + (size_t)b * M;
    float mx = -INFINITY; int mi = 0;
    for (int j = t; j < M; j += 1024) {
        float s = p[j] + p[j + (size_t)B * M] + p[j + 2 * (size_t)B * M]
                + p[j + 3 * (size_t)B * M];
        srow[j] = s;
        scoreF[(size_t)b * M + j] = s;
        if (s > mx) { mx = s; mi = j; }
    }
    rv[t] = mx; ri[t] = mi; __syncthreads();
    for (int s = 512; s > 0; s >>= 1) {
        if (t < s) {
            if (rv[t + s] > rv[t] || (rv[t + s] == rv[t] && ri[t + s] < ri[t])) {
                rv[t] = rv[t + s]; ri[t] = ri[t + s];
            }
        }
        __syncthreads();
    }
    float rmax = rv[0]; int rid = ri[0];
    __syncthreads();
    float s = 0.f;
    for (int j = t; j < M; j += 1024) {
        float e = expf(srow[j] - rmax);
        simgB[(size_t)b * M + j] = f2bf(e);  // unnormalized; 1/rowsum in k_out
        s += e;
    }
    rv[t] = s; __syncthreads();
    for (int ss = 512; ss > 0; ss >>= 1) {
        if (t < ss) rv[t] += rv[t + ss];
        __syncthreads();
    }
    if (t == 0) { idxout[b] = rid; rowinv[b] = 1.0f / rv[0]; }
}

// ---------------- K6: mr_p[z][b][c] MFMA bf16 (64x64 tile, no LDS) ---------
__global__ __launch_bounds__(256) void k_mr(const unsigned short* __restrict__ simgB,
                                            const unsigned short* __restrict__ memBT,
                                            float* __restrict__ mr_p) {
    int t = threadIdx.x;
    int lane = t & 63, wid = t >> 6;
    int wm = wid >> 1, wn = wid & 1;
    int brow = blockIdx.y * 64 + wm * 32;
    int ccol = blockIdx.x * 64 + wn * 32;
    int kc0 = blockIdx.z * (M / KS_MR);
    int l16 = lane & 15, kg = lane >> 4;
    f32x4 acc00 = {}, acc01 = {}, acc10 = {}, acc11 = {};
#pragma unroll 4
    for (int ks = 0; ks < M / KS_MR / 32; ++ks) {
        int kb = kc0 + ks * 32 + kg * 8;
        bf16x8 a0 = *reinterpret_cast<const bf16x8*>(simgB + (size_t)(brow + l16) * M + kb);
        bf16x8 a1 = *reinterpret_cast<const bf16x8*>(simgB + (size_t)(brow + 16 + l16) * M + kb);
        bf16x8 b0 = *reinterpret_cast<const bf16x8*>(memBT + (size_t)(ccol + l16) * M + kb);
        bf16x8 b1 = *reinterpret_cast<const bf16x8*>(memBT + (size_t)(ccol + 16 + l16) * M + kb);
        acc00 = __builtin_amdgcn_mfma_f32_16x16x32_bf16(a0, b0, acc00, 0, 0, 0);
        acc01 = __builtin_amdgcn_mfma_f32_16x16x32_bf16(a0, b1, acc01, 0, 0, 0);
        acc10 = __builtin_amdgcn_mfma_f32_16x16x32_bf16(a1, b0, acc10, 0, 0, 0);
        acc11 = __builtin_amdgcn_mfma_f32_16x16x32_bf16(a1, b1, acc11, 0, 0, 0);
    }
    float* o = mr_p + (size_t)blockIdx.z * B * C;
#pragma unroll
    for (int r = 0; r < 4; ++r) {
        int row0 = brow + kg * 4 + r, row1 = row0 + 16;
        o[(size_t)row0 * C + ccol + l16]      = acc00[r];
        o[(size_t)row0 * C + ccol + 16 + l16] = acc01[r];
        o[(size_t)row1 * C + ccol + l16]      = acc10[r];
        o[(size_t)row1 * C + ccol + 16 + l16] = acc11[r];
    }
}

// ---------------- K7 (fused mrred+out): out = f + fG + rinv*sum_z mr_p -----
// One wave per 16 descending rows. Per row: all lanes load partial z=lane&7,
// 3-step xor reduce within groups of 8 -> every lane holds the sum. Then the
// wave streams the 512-float row (2 fx4/lane), nontemporal stores.
__global__ __launch_bounds__(256) void k_out(const float* __restrict__ f,
                                             const float* __restrict__ mr_p,
                                             const float* __restrict__ fG,
                                             const float* __restrict__ rowinv,
                                             float* __restrict__ out) {
    int wave = blockIdx.x * 4 + (threadIdx.x >> 6);   // 0..16383
    int lane = threadIdx.x & 63;
    const size_t nrows = (size_t)B * C;               // 262144 = 16384 waves x 16
#pragma unroll 2
    for (int r = 0; r < 16; ++r) {
        size_t row = nrows - 1 - ((size_t)wave * 16 + r);   // descending rows
        float a = mr_p[(size_t)(lane & 7) * B * C + row];
        a += __shfl_xor(a, 1);
        a += __shfl_xor(a, 2);
        a += __shfl_xor(a, 4);
        a = fG[row] + rowinv[row >> 10] * a;
        const fx4* f4 = reinterpret_cast<const fx4*>(f) + row * 128;
        fx4* o4 = reinterpret_cast<fx4*>(out) + row * 128;
        fx4 v0 = f4[lane];
        fx4 v1 = f4[lane + 64];
        v0 += a; v1 += a;
        __builtin_nontemporal_store(v0, o4 + lane);
        __builtin_nontemporal_store(v1, o4 + lane + 64);
    }
}

// ---------------- K8: updated_memory row m (wts inline + L2-normalize) -----
__global__ __launch_bounds__(256) void k_memupd(const float* __restrict__ mem,
                                                const float* __restrict__ fG,
                                                const int* __restrict__ idx,
                                                const float* __restrict__ scoreF,
                                                float* __restrict__ out2) {
    int m = blockIdx.x, t = threadIdx.x;
    __shared__ int sIdx[B];
    __shared__ float se[B];
    __shared__ float red[256];
    __shared__ int sAny;
    if (t == 0) sAny = 0;
    __syncthreads();
    sIdx[t] = idx[t];
    __syncthreads();
    if (sIdx[t] == m) sAny = 1;   // benign same-value race
    __syncthreads();

    const fx4* m4 = reinterpret_cast<const fx4*>(mem) + (size_t)m * (C / 4);
    fx4 u = m4[t];
    if (sAny) {
        float x = scoreF[(size_t)t * M + m];
        red[t] = x; __syncthreads();
        for (int s = 128; s > 0; s >>= 1) {
            if (t < s) red[t] = fmaxf(red[t], red[t + s]);
            __syncthreads();
        }
        float mx = red[0]; __syncthreads();
        float e = expf(x - mx);
        se[t] = e;
        red[t] = e; __syncthreads();
        for (int s = 128; s > 0; s >>= 1) {
            if (t < s) red[t] += red[t + s];
            __syncthreads();
        }
        float Sinv = 1.0f / red[0];
        __syncthreads();
        for (int b2 = 0; b2 < B; ++b2) {
            if (sIdx[b2] == m) {
                float w = se[b2] * Sinv;
                fx4 g = reinterpret_cast<const fx4*>(fG)[(size_t)b2 * (C / 4) + t];
                u += g * w;
            }
        }
    }
    red[t] = u.x * u.x + u.y * u.y + u.z * u.z + u.w * u.w;
    __syncthreads();
    for (int s = 128; s > 0; s >>= 1) {
        if (t < s) red[t] += red[t + s];
        __syncthreads();
    }
    float invn = 1.0f / fmaxf(sqrtf(red[0]), EPS);
    reinterpret_cast<fx4*>(out2)[(size_t)m * (C / 4) + t] = u * invn;
}

extern "C" void kernel_launch(void* const* d_in, const int* in_sizes, int n_in,
                              void* d_out, int out_size, void* d_ws, size_t ws_size,
                              hipStream_t stream) {
    const float* feature = (const float*)d_in[0];  // [B,C,D]
    const float* memory  = (const float*)d_in[1];  // [M,C]
    float* out = (float*)d_out;

    // workspace layout: f32 buffers first, then u16 buffers
    float* ws = (float*)d_ws;
    float* colpart = ws;                                  // NCP*CHUNK*D = 4 MB
    float* attnD   = colpart + (size_t)NCP * CHUNK * D;   // B*D
    float* fG      = attnD + (size_t)B * D;               // B*C
    float* scoreF  = fG + (size_t)B * C;                  // B*M
    float* score_p = scoreF + (size_t)B * M;              // KS_SC*B*M = 16 MB
    float* mr_p    = score_p + (size_t)KS_SC * B * M;     // KS_MR*B*C = 8 MB
    float* rowinv  = mr_p + (size_t)KS_MR * B * C;        // B
    int*   idx     = (int*)(rowinv + B);                  // B
    unsigned short* fGB   = (unsigned short*)(idx + B);   // B*C u16
    unsigned short* memB  = fGB + (size_t)B * C;          // M*C u16 = 8 MB
    unsigned short* memBT = memB + (size_t)M * C;         // C*M u16 = 8 MB
    unsigned short* simgB = memBT + (size_t)C * M;        // B*M u16 = 2 MB

    k_convmem<<<dim3(M / 64, C / 64), 256, 0, stream>>>(memory, memB, memBT);
    for (int b0 = 0; b0 < B; b0 += CHUNK) {
        k_colmean<<<dim3(CHUNK, NCP), 256, 0, stream>>>(feature, colpart, b0);
        k_attn<<<CHUNK, 256, 0, stream>>>(colpart, attnD, b0);
        k_fg<<<CHUNK * C / 4, 256, 0, stream>>>(feature, attnD, fG, fGB, b0);
    }
    k_score<<<dim3(M / 64, B / 64, KS_SC), 256, 0, stream>>>(fGB, memB, score_p);
    k_rowsoftmax<<<B, 1024, 0, stream>>>(score_p, scoreF, simgB, idx, rowinv);
    k_mr<<<dim3(C / 64, B / 64, KS_MR), 256, 0, stream>>>(simgB, memBT, mr_p);
    k_out<<<4096, 256, 0, stream>>>(feature, mr_p, fG, rowinv, out);
    k_memupd<<<M, 256, 0, stream>>>(memory, fG, idx, scoreF, out + (size_t)B * C * D);
}

// Round 13
// 453.229 us; speedup vs baseline: 4.3479x; 1.0118x over previous
//
#include <hip/hip_runtime.h>
#include <math.h>

#define B 256
#define C 1024
#define D 512
#define M 4096
#define KS_SC 4    // K-split for score GEMM (K=1024 -> 256 per slice)
#define KS_MR 8    // K-split for mr GEMM    (K=4096 -> 512 per slice)
#define CHUNK 64   // b-chunk: 128 MB feature slice stays L3-resident for fg
#define CPB 32     // c-rows per colmean block
#define NCP (C / CPB)  // 32 c-partials per b
static constexpr float EPS = 1e-12f;

typedef float fx4 __attribute__((ext_vector_type(4)));   // nontemporal-OK
typedef short bf16x8 __attribute__((ext_vector_type(8))); // 8 bf16 = 4 VGPR
typedef float f32x4 __attribute__((ext_vector_type(4)));  // MFMA accumulator

static __device__ __forceinline__ unsigned short f2bf(float x) {
    unsigned u = __builtin_bit_cast(unsigned, x);
    return (unsigned short)((u + 0x7fffu + ((u >> 16) & 1u)) >> 16);  // RNE
}

// ---- colmean block body: colpart[cc][bx][d] = sum over 32 c-rows of b0+bx --
static __device__ __forceinline__ void colmean_body(const float* __restrict__ f,
                                                    float* __restrict__ colpart,
                                                    int b0, int idx, int t,
                                                    fx4* buf /*LDS, 128 elems*/) {
    int bx = idx & 63, cc = idx >> 6;
    int b = b0 + bx;
    int r = t >> 7, lane = t & 127;
    const fx4* f4 = reinterpret_cast<const fx4*>(f)
                  + ((size_t)b * C + cc * CPB + r * 16) * (D / 4) + lane;
    fx4 acc = (fx4)(0.f);
#pragma unroll
    for (int k = 0; k < 16; ++k) acc += f4[(size_t)k * (D / 4)];
    if (r) buf[lane] = acc;
    __syncthreads();
    if (!r) {
        acc += buf[lane];
        reinterpret_cast<fx4*>(colpart)[((size_t)cc * CHUNK + bx) * (D / 4) + lane] = acc;
    }
}

// ---------------- D1: convmem (1024 blocks) + colmean chunk 0 (2048) -------
__global__ __launch_bounds__(256) void k_conv_colmean(const float* __restrict__ mem,
                                                      unsigned short* __restrict__ memB,
                                                      unsigned short* __restrict__ memBT,
                                                      const float* __restrict__ f,
                                                      float* __restrict__ colpart) {
    __shared__ union { unsigned short cv[64][65]; fx4 cm[128]; } sm;
    int bid = blockIdx.x, t = threadIdx.x;
    if (bid < 1024) {
        // ---- convmem tile: memory f32 -> bf16 [M][C] and transposed [C][M]
        int tm = (bid & 63) * 64;   // M-tile
        int tc = (bid >> 6) * 64;   // C-tile
        int rr = t >> 4, c4 = t & 15;
#pragma unroll
        for (int i = 0; i < 4; ++i) {
            int row = rr + 16 * i;
            float4 v = *reinterpret_cast<const float4*>(mem + (size_t)(tm + row) * C + tc + c4 * 4);
            unsigned short b0 = f2bf(v.x), b1 = f2bf(v.y), b2 = f2bf(v.z), b3 = f2bf(v.w);
            ushort4 w = make_ushort4(b0, b1, b2, b3);
            *reinterpret_cast<ushort4*>(memB + (size_t)(tm + row) * C + tc + c4 * 4) = w;
            sm.cv[row][c4 * 4 + 0] = b0; sm.cv[row][c4 * 4 + 1] = b1;
            sm.cv[row][c4 * 4 + 2] = b2; sm.cv[row][c4 * 4 + 3] = b3;
        }
        __syncthreads();
#pragma unroll
        for (int i = 0; i < 4; ++i) {
            int colC = rr + 16 * i;
            ushort4 w = make_ushort4(sm.cv[c4 * 4 + 0][colC], sm.cv[c4 * 4 + 1][colC],
                                     sm.cv[c4 * 4 + 2][colC], sm.cv[c4 * 4 + 3][colC]);
            *reinterpret_cast<ushort4*>(memBT + (size_t)(tc + colC) * M + tm + c4 * 4) = w;
        }
    } else {
        colmean_body(f, colpart, 0, bid - 1024, t, sm.cm);
    }
}

// ---------------- K2: attnD[b][d] = softmax_d(colsum/C)/D ------------------
__global__ __launch_bounds__(256) void k_attn(const float* __restrict__ colpart,
                                              float* __restrict__ attnD, int b0) {
    __shared__ float red[256];
    int bl = blockIdx.x;
    int b = b0 + bl;
    int t = threadIdx.x;
    float s0 = 0.f, s1 = 0.f;
#pragma unroll
    for (int p = 0; p < NCP; ++p) {
        s0 += colpart[((size_t)p * CHUNK + bl) * D + t];
        s1 += colpart[((size_t)p * CHUNK + bl) * D + t + 256];
    }
    float x0 = s0 * (1.0f / C), x1 = s1 * (1.0f / C);
    red[t] = fmaxf(x0, x1); __syncthreads();
    for (int s = 128; s > 0; s >>= 1) {
        if (t < s) red[t] = fmaxf(red[t], red[t + s]);
        __syncthreads();
    }
    float mx = red[0]; __syncthreads();
    float e0 = expf(x0 - mx), e1 = expf(x1 - mx);
    red[t] = e0 + e1; __syncthreads();
    for (int s = 128; s > 0; s >>= 1) {
        if (t < s) red[t] += red[t + s];
        __syncthreads();
    }
    float inv = 1.0f / (red[0] * (float)D);
    attnD[(size_t)b * D + t] = e0 * inv;
    attnD[(size_t)b * D + t + 256] = e1 * inv;
}

// ---------------- D3/5/7/9: fg chunk i (+ colmean chunk i+1 when cm=1) -----
// colmean blocks FIRST (start the next chunk's HBM stream early); fg blocks
// read the current chunk from L3. Both chunks fit L3 (128+128 = 256 MB).
__global__ __launch_bounds__(256) void k_fg_colmean(const float* __restrict__ f,
                                                    const float* __restrict__ attnD,
                                                    float* __restrict__ fG,
                                                    unsigned short* __restrict__ fGB,
                                                    float* __restrict__ colpart,
                                                    int b0, int b0n, int cm) {
    __shared__ fx4 buf[128];
    int bid = blockIdx.x, t = threadIdx.x;
    int cmb = cm ? 2048 : 0;
    if (bid < cmb) {
        colmean_body(f, colpart, b0n, bid, t, buf);
        return;
    }
    int idx = bid - cmb;
    int w = idx * 4 + (t >> 6);
    int lane = t & 63;
    int b = b0 + (w >> 10);
    int c = w & 1023;
    const float4* f4 = reinterpret_cast<const float4*>(f) + ((size_t)b * C + c) * (D / 4);
    const float4* a4 = reinterpret_cast<const float4*>(attnD) + (size_t)b * (D / 4);
    float4 v0 = f4[lane], v1 = f4[lane + 64];
    float4 a0 = a4[lane], a1 = a4[lane + 64];
    float acc = v0.x * a0.x + v0.y * a0.y + v0.z * a0.z + v0.w * a0.w
              + v1.x * a1.x + v1.y * a1.y + v1.z * a1.z + v1.w * a1.w;
    for (int s = 32; s > 0; s >>= 1) acc += __shfl_xor(acc, s, 64);
    if (lane == 0) {
        fG[(size_t)b * C + c] = acc;
        fGB[(size_t)b * C + c] = f2bf(acc);
    }
}

// ---------------- K4: score_p[z][b][m] MFMA bf16 (64x64 tile, no LDS) ------
__global__ __launch_bounds__(256) void k_score(const unsigned short* __restrict__ fGB,
                                               const unsigned short* __restrict__ memB,
                                               float* __restrict__ score_p) {
    int t = threadIdx.x;
    int lane = t & 63, wid = t >> 6;
    int wm = wid >> 1, wn = wid & 1;
    int brow = blockIdx.y * 64 + wm * 32;
    int mcol = blockIdx.x * 64 + wn * 32;
    int kc0 = blockIdx.z * (C / KS_SC);
    int l16 = lane & 15, kg = lane >> 4;
    f32x4 acc00 = {}, acc01 = {}, acc10 = {}, acc11 = {};
#pragma unroll
    for (int ks = 0; ks < C / KS_SC / 32; ++ks) {
        int kb = kc0 + ks * 32 + kg * 8;
        bf16x8 a0 = *reinterpret_cast<const bf16x8*>(fGB + (size_t)(brow + l16) * C + kb);
        bf16x8 a1 = *reinterpret_cast<const bf16x8*>(fGB + (size_t)(brow + 16 + l16) * C + kb);
        bf16x8 b0 = *reinterpret_cast<const bf16x8*>(memB + (size_t)(mcol + l16) * C + kb);
        bf16x8 b1 = *reinterpret_cast<const bf16x8*>(memB + (size_t)(mcol + 16 + l16) * C + kb);
        acc00 = __builtin_amdgcn_mfma_f32_16x16x32_bf16(a0, b0, acc00, 0, 0, 0);
        acc01 = __builtin_amdgcn_mfma_f32_16x16x32_bf16(a0, b1, acc01, 0, 0, 0);
        acc10 = __builtin_amdgcn_mfma_f32_16x16x32_bf16(a1, b0, acc10, 0, 0, 0);
        acc11 = __builtin_amdgcn_mfma_f32_16x16x32_bf16(a1, b1, acc11, 0, 0, 0);
    }
    float* o = score_p + (size_t)blockIdx.z * B * M;
#pragma unroll
    for (int r = 0; r < 4; ++r) {
        int row0 = brow + kg * 4 + r, row1 = row0 + 16;
        o[(size_t)row0 * M + mcol + l16]      = acc00[r];
        o[(size_t)row0 * M + mcol + 16 + l16] = acc01[r];
        o[(size_t)row1 * M + mcol + l16]      = acc10[r];
        o[(size_t)row1 * M + mcol + 16 + l16] = acc11[r];
    }
}

// ---------------- K5: combine partials; row softmax; argmax ----------------
__global__ __launch_bounds__(1024) void k_rowsoftmax(const float* __restrict__ score_p,
                                                     unsigned short* __restrict__ simgB,
                                                     int* __restrict__ idxout,
                                                     float* __restrict__ rowinv) {
    __shared__ float srow[M];
    __shared__ float rv[1024];
    __shared__ int ri[1024];
    int b = blockIdx.x, t = threadIdx.x;
    const float* p = score_p + (size_t)b * M;
    float mx = -INFINITY; int mi = 0;
    for (int j = t; j < M; j += 1024) {
        float s = p[j] + p[j + (size_t)B * M] + p[j + 2 * (size_t)B * M]
                + p[j + 3 * (size_t)B * M];
        srow[j] = s;
        if (s > mx) { mx = s; mi = j; }
    }
    rv[t] = mx; ri[t] = mi; __syncthreads();
    for (int s = 512; s > 0; s >>= 1) {
        if (t < s) {
            if (rv[t + s] > rv[t] || (rv[t + s] == rv[t] && ri[t + s] < ri[t])) {
                rv[t] = rv[t + s]; ri[t] = ri[t + s];
            }
        }
        __syncthreads();
    }
    float rmax = rv[0]; int rid = ri[0];
    __syncthreads();
    float s = 0.f;
    for (int j = t; j < M; j += 1024) {
        float e = expf(srow[j] - rmax);
        simgB[(size_t)b * M + j] = f2bf(e);  // unnormalized; 1/rowsum in k_out
        s += e;
    }
    rv[t] = s; __syncthreads();
    for (int ss = 512; ss > 0; ss >>= 1) {
        if (t < ss) rv[t] += rv[t + ss];
        __syncthreads();
    }
    if (t == 0) { idxout[b] = rid; rowinv[b] = 1.0f / rv[0]; }
}

// ---------------- K6: mr_p[z][b][c] MFMA bf16 (64x64 tile, no LDS) ---------
__global__ __launch_bounds__(256) void k_mr(const unsigned short* __restrict__ simgB,
                                            const unsigned short* __restrict__ memBT,
                                            float* __restrict__ mr_p) {
    int t = threadIdx.x;
    int lane = t & 63, wid = t >> 6;
    int wm = wid >> 1, wn = wid & 1;
    int brow = blockIdx.y * 64 + wm * 32;
    int ccol = blockIdx.x * 64 + wn * 32;
    int kc0 = blockIdx.z * (M / KS_MR);
    int l16 = lane & 15, kg = lane >> 4;
    f32x4 acc00 = {}, acc01 = {}, acc10 = {}, acc11 = {};
#pragma unroll 4
    for (int ks = 0; ks < M / KS_MR / 32; ++ks) {
        int kb = kc0 + ks * 32 + kg * 8;
        bf16x8 a0 = *reinterpret_cast<const bf16x8*>(simgB + (size_t)(brow + l16) * M + kb);
        bf16x8 a1 = *reinterpret_cast<const bf16x8*>(simgB + (size_t)(brow + 16 + l16) * M + kb);
        bf16x8 b0 = *reinterpret_cast<const bf16x8*>(memBT + (size_t)(ccol + l16) * M + kb);
        bf16x8 b1 = *reinterpret_cast<const bf16x8*>(memBT + (size_t)(ccol + 16 + l16) * M + kb);
        acc00 = __builtin_amdgcn_mfma_f32_16x16x32_bf16(a0, b0, acc00, 0, 0, 0);
        acc01 = __builtin_amdgcn_mfma_f32_16x16x32_bf16(a0, b1, acc01, 0, 0, 0);
        acc10 = __builtin_amdgcn_mfma_f32_16x16x32_bf16(a1, b0, acc10, 0, 0, 0);
        acc11 = __builtin_amdgcn_mfma_f32_16x16x32_bf16(a1, b1, acc11, 0, 0, 0);
    }
    float* o = mr_p + (size_t)blockIdx.z * B * C;
#pragma unroll
    for (int r = 0; r < 4; ++r) {
        int row0 = brow + kg * 4 + r, row1 = row0 + 16;
        o[(size_t)row0 * C + ccol + l16]      = acc00[r];
        o[(size_t)row0 * C + ccol + 16 + l16] = acc01[r];
        o[(size_t)row1 * C + ccol + l16]      = acc10[r];
        o[(size_t)row1 * C + ccol + 16 + l16] = acc11[r];
    }
}

// ---------------- D13: k_out (blocks 0..4095) + k_memupd (4096..8191) ------
__global__ __launch_bounds__(256) void k_out_memupd(const float* __restrict__ f,
                                                    const float* __restrict__ mr_p,
                                                    const float* __restrict__ fG,
                                                    const float* __restrict__ rowinv,
                                                    const float* __restrict__ mem,
                                                    const int* __restrict__ idx,
                                                    const float* __restrict__ score_p,
                                                    float* __restrict__ out,
                                                    float* __restrict__ out2) {
    __shared__ int sIdx[B];
    __shared__ float se[B];
    __shared__ float red[256];
    __shared__ int sAny;
    int bid = blockIdx.x, t = threadIdx.x;
    if (bid < 4096) {
        // ---- out = feature + fG + rinv * sum_z mr_p, rows DESCENDING ------
        int wave = bid * 4 + (t >> 6);
        int lane = t & 63;
        const size_t nrows = (size_t)B * C;
#pragma unroll 2
        for (int r = 0; r < 16; ++r) {
            size_t row = nrows - 1 - ((size_t)wave * 16 + r);
            float a = mr_p[(size_t)(lane & 7) * B * C + row];
            a += __shfl_xor(a, 1);
            a += __shfl_xor(a, 2);
            a += __shfl_xor(a, 4);
            a = fG[row] + rowinv[row >> 10] * a;
            const fx4* f4 = reinterpret_cast<const fx4*>(f) + row * 128;
            fx4* o4 = reinterpret_cast<fx4*>(out) + row * 128;
            fx4 v0 = f4[lane];
            fx4 v1 = f4[lane + 64];
            v0 += a; v1 += a;
            __builtin_nontemporal_store(v0, o4 + lane);
            __builtin_nontemporal_store(v1, o4 + lane + 64);
        }
        return;
    }
    // ---- memupd row m (inline column softmax over batch; L2-normalize) ----
    int m = bid - 4096;
    if (t == 0) sAny = 0;
    __syncthreads();
    sIdx[t] = idx[t];
    __syncthreads();
    if (sIdx[t] == m) sAny = 1;   // benign same-value race
    __syncthreads();
    const fx4* m4 = reinterpret_cast<const fx4*>(mem) + (size_t)m * (C / 4);
    fx4 u = m4[t];
    if (sAny) {
        size_t o = (size_t)t * M + m;
        float x = score_p[o] + score_p[o + (size_t)B * M]
                + score_p[o + 2 * (size_t)B * M] + score_p[o + 3 * (size_t)B * M];
        red[t] = x; __syncthreads();
        for (int s = 128; s > 0; s >>= 1) {
            if (t < s) red[t] = fmaxf(red[t], red[t + s]);
            __syncthreads();
        }
        float mx = red[0]; __syncthreads();
        float e = expf(x - mx);
        se[t] = e;
        red[t] = e; __syncthreads();
        for (int s = 128; s > 0; s >>= 1) {
            if (t < s) red[t] += red[t + s];
            __syncthreads();
        }
        float Sinv = 1.0f / red[0];
        __syncthreads();
        for (int b2 = 0; b2 < B; ++b2) {
            if (sIdx[b2] == m) {
                float w = se[b2] * Sinv;
                fx4 g = reinterpret_cast<const fx4*>(fG)[(size_t)b2 * (C / 4) + t];
                u += g * w;
            }
        }
    }
    red[t] = u.x * u.x + u.y * u.y + u.z * u.z + u.w * u.w;
    __syncthreads();
    for (int s = 128; s > 0; s >>= 1) {
        if (t < s) red[t] += red[t + s];
        __syncthreads();
    }
    float invn = 1.0f / fmaxf(sqrtf(red[0]), EPS);
    reinterpret_cast<fx4*>(out2)[(size_t)m * (C / 4) + t] = u * invn;
}

extern "C" void kernel_launch(void* const* d_in, const int* in_sizes, int n_in,
                              void* d_out, int out_size, void* d_ws, size_t ws_size,
                              hipStream_t stream) {
    const float* feature = (const float*)d_in[0];  // [B,C,D]
    const float* memory  = (const float*)d_in[1];  // [M,C]
    float* out = (float*)d_out;

    // workspace layout: f32 buffers first, then u16 buffers
    float* ws = (float*)d_ws;
    float* colpart = ws;                                  // NCP*CHUNK*D = 4 MB
    float* attnD   = colpart + (size_t)NCP * CHUNK * D;   // B*D
    float* fG      = attnD + (size_t)B * D;               // B*C
    float* score_p = fG + (size_t)B * C;                  // KS_SC*B*M = 16 MB
    float* mr_p    = score_p + (size_t)KS_SC * B * M;     // KS_MR*B*C = 8 MB
    float* rowinv  = mr_p + (size_t)KS_MR * B * C;        // B
    int*   idx     = (int*)(rowinv + B);                  // B
    unsigned short* fGB   = (unsigned short*)(idx + B);   // B*C u16
    unsigned short* memB  = fGB + (size_t)B * C;          // M*C u16 = 8 MB
    unsigned short* memBT = memB + (size_t)M * C;         // C*M u16 = 8 MB
    unsigned short* simgB = memBT + (size_t)C * M;        // B*M u16 = 2 MB

    // D1: convmem + colmean chunk 0
    k_conv_colmean<<<3072, 256, 0, stream>>>(memory, memB, memBT, feature, colpart);
    // chunk pipeline: attn(i); fg(i) overlapped with colmean(i+1)
    for (int i = 0; i < 4; ++i) {
        int b0 = i * CHUNK;
        k_attn<<<CHUNK, 256, 0, stream>>>(colpart, attnD, b0);
        int cm = (i < 3) ? 1 : 0;
        k_fg_colmean<<<cm ? 18432 : 16384, 256, 0, stream>>>(
            feature, attnD, fG, fGB, colpart, b0, b0 + CHUNK, cm);
    }
    k_score<<<dim3(M / 64, B / 64, KS_SC), 256, 0, stream>>>(fGB, memB, score_p);
    k_rowsoftmax<<<B, 1024, 0, stream>>>(score_p, simgB, idx, rowinv);
    k_mr<<<dim3(C / 64, B / 64, KS_MR), 256, 0, stream>>>(simgB, memBT, mr_p);
    k_out_memupd<<<8192, 256, 0, stream>>>(feature, mr_p, fG, rowinv, memory, idx,
                                           score_p, out, out + (size_t)B * C * D);
}